// Round 9
// baseline (160.534 us; speedup 1.0000x reference)
//
#include <hip/hip_runtime.h>
#include <stdint.h>

#define DEV __device__ __forceinline__

typedef uint32_t u32;
typedef uint16_t u16;
typedef __attribute__((ext_vector_type(4))) float f32x4;
typedef __attribute__((ext_vector_type(8))) __bf16 bf16x8;

DEV u16 f32_to_bf16(float f) {
  u32 u = __builtin_bit_cast(u32, f);
  u += 0x7FFFu + ((u >> 16) & 1u);
  return (u16)(u >> 16);
}
DEV float bf16_to_f32(u16 h) {
  u32 u = ((u32)h) << 16;
  return __builtin_bit_cast(float, u);
}
DEV bf16x8 load_frag16(const u16* p) {
  return __builtin_bit_cast(bf16x8, *(const uint4*)p);
}
DEV float exp2_fast(float x) {
#if __has_builtin(__builtin_amdgcn_exp2f)
  return __builtin_amdgcn_exp2f(x);
#else
  float r;
  asm("v_exp_f32 %0, %1\n\ts_nop 0" : "=v"(r) : "v"(x));
  return r;
#endif
}
DEV u32 cvt_pk_bf16(float lo, float hi) {
  u32 r;
  asm("v_cvt_pk_bf16_f32 %0, %1, %2" : "=v"(r) : "v"(lo), "v"(hi));
  return r;
}

// global -> LDS direct (16B per lane, dest = wave-uniform base + lane*16)
DEV void gl_lds16(const u16* g, u16* l) {
  __builtin_amdgcn_global_load_lds(
      (__attribute__((address_space(1))) void*)(u16*)g,
      (__attribute__((address_space(3))) void*)l, 16, 0, 0);
}

// XOR-swizzled address into a [rows][64 bf16] tile (128 B rows).
DEV const u16* swz(const u16* basep, int row, int colByte) {
  return (const u16*)((const char*)basep + row * 128 + (colByte ^ ((row & 7) << 4)));
}
DEV u16* swzw(u16* basep, int row, int colByte) {
  return (u16*)((char*)basep + row * 128 + (colByte ^ ((row & 7) << 4)));
}

// ---------------- convert fp32 -> bf16 (elementwise) ----------------
__global__ void cvt_f32_bf16(const float* __restrict__ in, u16* __restrict__ out, int n) {
  int i = (blockIdx.x * 256 + threadIdx.x) * 4;
  if (i >= n) return;
  float4 v = *(const float4*)(in + i);
  ushort4 o;
  o.x = f32_to_bf16(v.x); o.y = f32_to_bf16(v.y);
  o.z = f32_to_bf16(v.z); o.w = f32_to_bf16(v.w);
  *(ushort4*)(out + i) = o;
}

// ------ fused transpose+convert for both weights (one launch) ------
// grid (128, 32): x<96 -> Wqkv [1024][3072] -> wqT [3072][1024];
//                 x>=96 -> Wproj [1024][1024] -> wpT [1024][1024].
__global__ void transpose_cvt2(const float* __restrict__ inA, u16* __restrict__ outA,
                               const float* __restrict__ inB, u16* __restrict__ outB) {
  __shared__ float tile[32][33];
  const float* in; u16* out; int C; int bxi;
  if (blockIdx.x < 96) { in = inA; out = outA; C = 3072; bxi = blockIdx.x; }
  else { in = inB; out = outB; C = 1024; bxi = blockIdx.x - 96; }
  const int R = 1024;
  int bx = bxi * 32;
  int by = blockIdx.y * 32;
  int tx = threadIdx.x & 31;
  int ty = threadIdx.x >> 5;
#pragma unroll
  for (int i = 0; i < 32; i += 8)
    tile[ty + i][tx] = in[(size_t)(by + ty + i) * C + bx + tx];
  __syncthreads();
#pragma unroll
  for (int i = 0; i < 32; i += 8)
    out[(size_t)(bx + ty + i) * R + by + tx] = f32_to_bf16(tile[tx][ty + i]);
}

// ---------------- bf16 GEMM 128x128: C = A * Bt^T + bias ----------------
// MODE 0: C = float [M][N].
// MODE 2: QKV-fused. Columns <2048 (Q|K) -> bf16 qkb with row stride 2048.
//         Columns >=2048 (V) -> written TRANSPOSED into vTg[bh][64][2048].
template <int MODE>
__global__ __launch_bounds__(256, 2) void gemm_bf16(
    const u16* __restrict__ A, const u16* __restrict__ Bt,
    const float* __restrict__ bias, void* __restrict__ Cout,
    int M, int N, int K, u16* __restrict__ vTg) {
  __shared__ __attribute__((aligned(16))) u16 As[128 * 64];
  __shared__ __attribute__((aligned(16))) u16 Bs[128 * 64];
  int tid = threadIdx.x;
  u32 nwg = gridDim.x * gridDim.y;
  u32 orig = blockIdx.y * gridDim.x + blockIdx.x;
  u32 wg = (orig & 7) * (nwg >> 3) + (orig >> 3);
  int m0 = (wg / gridDim.x) * 128;
  int n0 = (wg % gridDim.x) * 128;
  int w = tid >> 6, l = tid & 63;
  int wr = w >> 1, wc = w & 1;
  int lr = l & 15, lg = l >> 4;
  int rloc = l >> 3, cc = l & 7;
  int scc8 = (cc ^ rloc) * 8;

  f32x4 acc[4][4];
#pragma unroll
  for (int i = 0; i < 4; i++)
#pragma unroll
    for (int j = 0; j < 4; j++) acc[i][j] = (f32x4)0.0f;

  for (int kt = 0; kt < K; kt += 64) {
    __syncthreads();
#pragma unroll
    for (int qq = 0; qq < 4; ++qq) {
      int row = 32 * w + 8 * qq + rloc;
      gl_lds16(A + (size_t)(m0 + row) * K + kt + scc8, &As[(32 * w + 8 * qq) * 64]);
      gl_lds16(Bt + (size_t)(n0 + row) * K + kt + scc8, &Bs[(32 * w + 8 * qq) * 64]);
    }
    __syncthreads();
#pragma unroll
    for (int kk = 0; kk < 2; ++kk) {
      bf16x8 af[4], bfr[4];
#pragma unroll
      for (int i = 0; i < 4; i++)
        af[i] = load_frag16(swz(As, wr * 64 + i * 16 + lr, kk * 64 + lg * 16));
#pragma unroll
      for (int j = 0; j < 4; j++)
        bfr[j] = load_frag16(swz(Bs, wc * 64 + j * 16 + lr, kk * 64 + lg * 16));
#pragma unroll
      for (int i = 0; i < 4; i++)
#pragma unroll
        for (int j = 0; j < 4; j++)
          acc[i][j] = __builtin_amdgcn_mfma_f32_16x16x32_bf16(af[i], bfr[j], acc[i][j], 0, 0, 0);
    }
  }

  if (MODE == 0) {
#pragma unroll
    for (int i = 0; i < 4; i++) {
#pragma unroll
      for (int j = 0; j < 4; j++) {
        int col = n0 + wc * 64 + j * 16 + lr;
        float bv = bias[col];
#pragma unroll
        for (int r = 0; r < 4; r++) {
          int row = m0 + wr * 64 + i * 16 + lg * 4 + r;
          ((float*)Cout)[(size_t)row * N + col] = acc[i][j][r] + bv;
        }
      }
    }
  } else {
    if (n0 < 2048) {
      // Q|K slice -> qkb bf16, row stride 2048
#pragma unroll
      for (int i = 0; i < 4; i++) {
#pragma unroll
        for (int j = 0; j < 4; j++) {
          int col = n0 + wc * 64 + j * 16 + lr;
          float bv = bias[col];
#pragma unroll
          for (int r = 0; r < 4; r++) {
            int row = m0 + wr * 64 + i * 16 + lg * 4 + r;
            ((u16*)Cout)[(size_t)row * 2048 + col] = f32_to_bf16(acc[i][j][r] + bv);
          }
        }
      }
    } else {
      // V slice -> vTg[bh][64][2048] transposed; 4 consecutive l per lane = 8B chunk
#pragma unroll
      for (int i = 0; i < 4; i++) {
        int row0 = m0 + wr * 64 + i * 16 + lg * 4;
        int bq = row0 >> 11;
        int l0 = row0 & 2047;
#pragma unroll
        for (int j = 0; j < 4; j++) {
          int col = n0 + wc * 64 + j * 16 + lr;
          float bv = bias[col];
          int d = col - 2048;
          int h = d >> 6, hd = d & 63;
          uint2 pk;
          pk.x = cvt_pk_bf16(acc[i][j][0] + bv, acc[i][j][1] + bv);
          pk.y = cvt_pk_bf16(acc[i][j][2] + bv, acc[i][j][3] + bv);
          *(uint2*)(vTg + ((size_t)(bq * 16 + h) * 64 + hd) * 2048 + l0) = pk;
        }
      }
    }
  }
}

// ---------------- causal flash attention (v5 — round-7 passing structure) ----------------
// qkb: [B*L][2048] bf16 (Q|K). vTg: [bh][64][2048] bf16. attnb: [B*L][1024] bf16.
// 256 threads (4 waves), 128 q-rows per block. grid (8, 64), XCD-swizzled so
// all 8 q-blocks of one (b,h) share an XCD's L2. K and V staged 128 rows per
// phase (two 64x64 swizzled sub-tiles each), double-buffered.
__global__ __launch_bounds__(256, 2) void attn_kernel(
    const u16* __restrict__ qkb, const u16* __restrict__ vTg,
    u16* __restrict__ attnb) {
  __shared__ __attribute__((aligned(16))) u16 Ks[2][2 * 64 * 64];
  __shared__ __attribute__((aligned(16))) u16 Vt[2][2 * 64 * 64];
  __shared__ __attribute__((aligned(16))) u16 Pl[4][32 * 64];
  int tid = threadIdx.x;
  int w = tid >> 6, l = tid & 63;
  int lr = l & 15, lg = l >> 4;
  int rloc = l >> 3, cc = l & 7;
  int scc8 = (cc ^ rloc) * 8;
  u32 orig = blockIdx.y * 8 + blockIdx.x;
  u32 wg = (orig & 7) * 64 + (orig >> 3);
  int bx = wg & 7;
  int bh = wg >> 3;
  int b = bh >> 4, h = bh & 15;
  const u16* base = qkb + (size_t)b * 2048 * 2048;
  const u16* kglob = base + 1024 + h * 64;
  const u16* vbase = vTg + (size_t)bh * 64 * 2048;
  u16* PlW = Pl[w];
  int usub = w >> 1, wl = w & 1;
  const float SCALE = 0.18033688011112042f;  // 0.125 * log2(e)

#define STAGE128(bi, tt)                                                        \
  do {                                                                          \
    int kv0_ = (tt) * 128;                                                      \
    _Pragma("unroll")                                                           \
    for (int qq = 0; qq < 4; ++qq) {                                            \
      int lrow_ = 32 * wl + 8 * qq;                                             \
      gl_lds16(kglob + (size_t)(kv0_ + usub * 64 + lrow_ + rloc) * 2048 + scc8, \
               &Ks[bi][usub * 4096 + lrow_ * 64]);                              \
      gl_lds16(vbase + (size_t)(lrow_ + rloc) * 2048 + kv0_ + usub * 64 + scc8, \
               &Vt[bi][usub * 4096 + lrow_ * 64]);                              \
    }                                                                           \
  } while (0)

  for (int half = 0; half < 2; ++half) {
    int s = half ? 15 - bx : bx;
    int qb = s * 128;
    int nst = s + 1;
    int tmax64 = 2 * s + (w >> 1);

    bf16x8 qf[2][2];
#pragma unroll
    for (int i = 0; i < 2; i++)
#pragma unroll
      for (int kk = 0; kk < 2; kk++) {
        int row = qb + w * 32 + i * 16 + lr;
        uint4 v = *(const uint4*)(base + (size_t)row * 2048 + h * 64 + kk * 32 + lg * 8);
        u32 wd[4] = {v.x, v.y, v.z, v.w};
#pragma unroll
        for (int e = 0; e < 4; e++) {
          float flo = bf16_to_f32((u16)(wd[e] & 0xFFFFu)) * SCALE;
          float fhi = bf16_to_f32((u16)(wd[e] >> 16)) * SCALE;
          wd[e] = cvt_pk_bf16(flo, fhi);
        }
        uint4 sv; sv.x = wd[0]; sv.y = wd[1]; sv.z = wd[2]; sv.w = wd[3];
        qf[i][kk] = __builtin_bit_cast(bf16x8, sv);
      }

    float m_st[2] = {-1e30f, -1e30f};
    float l_st[2] = {0.f, 0.f};
    f32x4 of[2][4];
#pragma unroll
    for (int i = 0; i < 2; i++)
#pragma unroll
      for (int j = 0; j < 4; j++) of[i][j] = (f32x4)0.0f;

    STAGE128(0, 0);

    for (int t = 0; t < nst; ++t) {
      int cur = t & 1;
      __syncthreads();  // staged data for t arrived; all waves done with buf cur
      if (t + 1 < nst) STAGE128(cur ^ 1, t + 1);

#pragma unroll
      for (int u = 0; u < 2; ++u) {
        int t64 = 2 * t + u;
        if (t64 <= tmax64) {
          const u16* Kb = Ks[cur] + u * 4096;
          const u16* Vb = Vt[cur] + u * 4096;

          f32x4 St[4][2];
#pragma unroll
          for (int j = 0; j < 4; j++)
#pragma unroll
            for (int i = 0; i < 2; i++) St[j][i] = (f32x4)0.0f;
          __builtin_amdgcn_s_setprio(1);
#pragma unroll
          for (int kk = 0; kk < 2; ++kk) {
            bf16x8 kbf[4];
#pragma unroll
            for (int j = 0; j < 4; j++)
              kbf[j] = load_frag16(swz(Kb, j * 16 + lr, kk * 64 + lg * 16));
#pragma unroll
            for (int j = 0; j < 4; j++)
#pragma unroll
              for (int i = 0; i < 2; i++)
                St[j][i] = __builtin_amdgcn_mfma_f32_16x16x32_bf16(kbf[j], qf[i][kk], St[j][i], 0, 0, 0);
          }
          __builtin_amdgcn_s_setprio(0);

          if (t64 == tmax64) {  // diagonal tile: mask k > q
#pragma unroll
            for (int j = 0; j < 4; j++)
#pragma unroll
              for (int i = 0; i < 2; i++)
#pragma unroll
                for (int r = 0; r < 4; r++) {
                  int kabs = t64 * 64 + j * 16 + lg * 4 + r;
                  int qabs = qb + w * 32 + i * 16 + lr;
                  if (kabs > qabs) St[j][i][r] = -1e30f;
                }
          }

          // lane-local online softmax (log2 domain), defer-max THR=10
#pragma unroll
          for (int i = 0; i < 2; ++i) {
            float tj[4];
#pragma unroll
            for (int j = 0; j < 4; j++)
              tj[j] = fmaxf(fmaxf(St[j][i][0], St[j][i][1]),
                            fmaxf(St[j][i][2], St[j][i][3]));
            float tm = fmaxf(fmaxf(tj[0], tj[1]), fmaxf(tj[2], tj[3]));
            tm = fmaxf(tm, __shfl_xor(tm, 16));
            tm = fmaxf(tm, __shfl_xor(tm, 32));
            if (!__all((int)(tm <= m_st[i] + 10.0f))) {
              float mn = fmaxf(m_st[i], tm);
              float fsc = exp2_fast(m_st[i] - mn);
              m_st[i] = mn;
              l_st[i] *= fsc;
#pragma unroll
              for (int r = 0; r < 4; ++r) {
                float ff = __shfl(fsc, lg * 4 + r);
#pragma unroll
                for (int jd = 0; jd < 4; jd++) of[i][jd][r] *= ff;
              }
            }
            float rj[4];
#pragma unroll
            for (int j = 0; j < 4; ++j) {
              float p0 = exp2_fast(St[j][i][0] - m_st[i]);
              float p1 = exp2_fast(St[j][i][1] - m_st[i]);
              float p2 = exp2_fast(St[j][i][2] - m_st[i]);
              float p3 = exp2_fast(St[j][i][3] - m_st[i]);
              rj[j] = (p0 + p1) + (p2 + p3);
              uint2 pk;
              pk.x = cvt_pk_bf16(p0, p1);
              pk.y = cvt_pk_bf16(p2, p3);
              *(uint2*)swzw(PlW, i * 16 + lr, j * 32 + lg * 8) = pk;
            }
            float rs = (rj[0] + rj[1]) + (rj[2] + rj[3]);
            rs += __shfl_xor(rs, 16);
            rs += __shfl_xor(rs, 32);
            l_st[i] += rs;
          }

          // PV: O[q][d] += P[q][k] * V[k][d]
          __builtin_amdgcn_s_setprio(1);
#pragma unroll
          for (int ks = 0; ks < 2; ++ks) {
            bf16x8 ap[2], vbf[4];
#pragma unroll
            for (int i = 0; i < 2; i++)
              ap[i] = load_frag16(swz(PlW, i * 16 + lr, ks * 64 + lg * 16));
#pragma unroll
            for (int jd = 0; jd < 4; jd++)
              vbf[jd] = load_frag16(swz(Vb, jd * 16 + lr, ks * 64 + lg * 16));
#pragma unroll
            for (int i = 0; i < 2; i++)
#pragma unroll
              for (int jd = 0; jd < 4; jd++)
                of[i][jd] = __builtin_amdgcn_mfma_f32_16x16x32_bf16(ap[i], vbf[jd], of[i][jd], 0, 0, 0);
          }
          __builtin_amdgcn_s_setprio(0);
        }
      }
    }
    __syncthreads();  // protect staging buffers before next half / exit

    // epilogue: O /= lsum, store bf16 head-merged
#pragma unroll
    for (int i = 0; i < 2; i++) {
#pragma unroll
      for (int r = 0; r < 4; r++) {
        float ls = __shfl(l_st[i], lg * 4 + r);
        float inv = 1.0f / ls;
#pragma unroll
        for (int jd = 0; jd < 4; jd++) {
          int row = qb + w * 32 + i * 16 + lg * 4 + r;
          int col = h * 64 + jd * 16 + lr;
          attnb[((size_t)b * 2048 + row) * 1024 + col] = f32_to_bf16(of[i][jd][r] * inv);
        }
      }
    }
  }
#undef STAGE128
}

extern "C" void kernel_launch(void* const* d_in, const int* in_sizes, int n_in,
                              void* d_out, int out_size, void* d_ws, size_t ws_size,
                              hipStream_t stream) {
  const float* x = (const float*)d_in[0];
  const float* Wqkv = (const float*)d_in[1];
  const float* bqkv = (const float*)d_in[2];
  const float* Wproj = (const float*)d_in[3];
  const float* bproj = (const float*)d_in[4];
  float* out = (float*)d_out;

  char* ws = (char*)d_ws;
  u16* xb    = (u16*)(ws);                 // 8192*1024*2 = 16,777,216
  u16* wqT   = (u16*)(ws + 16777216);      // 3072*1024*2 =  6,291,456
  u16* wpT   = (u16*)(ws + 23068672);      // 1024*1024*2 =  2,097,152
  u16* qkb   = (u16*)(ws + 25165824);      // 8192*2048*2 = 33,554,432 (Q|K)
  u16* vTg   = (u16*)(ws + 58720256);      // 64*64*2048*2= 16,777,216
  u16* attnb = (u16*)(ws + 75497472);      // 8192*1024*2 = 16,777,216  (total ~92MB)

  cvt_f32_bf16<<<8192, 256, 0, stream>>>(x, xb, 8388608);
  transpose_cvt2<<<dim3(128, 32), 256, 0, stream>>>(Wqkv, wqT, Wproj, wpT);
  gemm_bf16<2><<<dim3(24, 64), 256, 0, stream>>>(xb, wqT, bqkv, (void*)qkb, 8192, 3072, 1024, vTg);
  attn_kernel<<<dim3(8, 64), 256, 0, stream>>>(qkb, vTg, attnb);
  gemm_bf16<0><<<dim3(8, 64), 256, 0, stream>>>(attnb, wpT, bproj, (void*)out, 8192, 1024, 1024, nullptr);
}

// Round 11
// 156.189 us; speedup vs baseline: 1.0278x; 1.0278x over previous
//
#include <hip/hip_runtime.h>
#include <stdint.h>

#define DEV __device__ __forceinline__

typedef uint32_t u32;
typedef uint16_t u16;
typedef __attribute__((ext_vector_type(4))) float f32x4;
typedef __attribute__((ext_vector_type(8))) __bf16 bf16x8;

DEV u16 f32_to_bf16(float f) {
  u32 u = __builtin_bit_cast(u32, f);
  u += 0x7FFFu + ((u >> 16) & 1u);
  return (u16)(u >> 16);
}
DEV float bf16_to_f32(u16 h) {
  u32 u = ((u32)h) << 16;
  return __builtin_bit_cast(float, u);
}
DEV bf16x8 load_frag16(const u16* p) {
  return __builtin_bit_cast(bf16x8, *(const uint4*)p);
}
DEV float exp2_fast(float x) {
#if __has_builtin(__builtin_amdgcn_exp2f)
  return __builtin_amdgcn_exp2f(x);
#else
  float r;
  asm("v_exp_f32 %0, %1\n\ts_nop 0" : "=v"(r) : "v"(x));
  return r;
#endif
}
DEV u32 cvt_pk_bf16(float lo, float hi) {
  u32 r;
  asm("v_cvt_pk_bf16_f32 %0, %1, %2" : "=v"(r) : "v"(lo), "v"(hi));
  return r;
}

// global -> LDS direct (16B per lane, dest = wave-uniform base + lane*16)
DEV void gl_lds16(const u16* g, u16* l) {
  __builtin_amdgcn_global_load_lds(
      (__attribute__((address_space(1))) void*)(u16*)g,
      (__attribute__((address_space(3))) void*)l, 16, 0, 0);
}

// XOR-swizzled address into a [rows][64 bf16] tile (128 B rows).
DEV const u16* swz(const u16* basep, int row, int colByte) {
  return (const u16*)((const char*)basep + row * 128 + (colByte ^ ((row & 7) << 4)));
}
DEV u16* swzw(u16* basep, int row, int colByte) {
  return (u16*)((char*)basep + row * 128 + (colByte ^ ((row & 7) << 4)));
}

// ---------------- convert fp32 -> bf16 (elementwise) ----------------
__global__ void cvt_f32_bf16(const float* __restrict__ in, u16* __restrict__ out, int n) {
  int i = (blockIdx.x * 256 + threadIdx.x) * 4;
  if (i >= n) return;
  float4 v = *(const float4*)(in + i);
  ushort4 o;
  o.x = f32_to_bf16(v.x); o.y = f32_to_bf16(v.y);
  o.z = f32_to_bf16(v.z); o.w = f32_to_bf16(v.w);
  *(ushort4*)(out + i) = o;
}

// ------ fused transpose+convert for both weights (one launch) ------
__global__ void transpose_cvt2(const float* __restrict__ inA, u16* __restrict__ outA,
                               const float* __restrict__ inB, u16* __restrict__ outB) {
  __shared__ float tile[32][33];
  const float* in; u16* out; int C; int bxi;
  if (blockIdx.x < 96) { in = inA; out = outA; C = 3072; bxi = blockIdx.x; }
  else { in = inB; out = outB; C = 1024; bxi = blockIdx.x - 96; }
  const int R = 1024;
  int bx = bxi * 32;
  int by = blockIdx.y * 32;
  int tx = threadIdx.x & 31;
  int ty = threadIdx.x >> 5;
#pragma unroll
  for (int i = 0; i < 32; i += 8)
    tile[ty + i][tx] = in[(size_t)(by + ty + i) * C + bx + tx];
  __syncthreads();
#pragma unroll
  for (int i = 0; i < 32; i += 8)
    out[(size_t)(bx + ty + i) * R + by + tx] = f32_to_bf16(tile[tx][ty + i]);
}

// ---------------- bf16 GEMM 128x128: C = A * Bt^T + bias ----------------
// MODE 0: C = float [M][N].
// MODE 2: QKV-fused. Columns <2048 (Q|K) -> bf16 qkb with row stride 2048.
//         Columns >=2048 (V) -> written TRANSPOSED into vTg[bh][64][2048].
// Block mapping: XCD chunk (orig&7) then M-FASTEST within the chunk, so one
// 256KB B-panel is shared by 8 consecutive blocks and the chunk's 2MB A set
// stays L2-resident across all n-cols. Requires gridDim.y==64, nwg%8==0.
template <int MODE>
__global__ __launch_bounds__(256, 2) void gemm_bf16(
    const u16* __restrict__ A, const u16* __restrict__ Bt,
    const float* __restrict__ bias, void* __restrict__ Cout,
    int M, int N, int K, u16* __restrict__ vTg) {
  __shared__ __attribute__((aligned(16))) u16 As[128 * 64];
  __shared__ __attribute__((aligned(16))) u16 Bs[128 * 64];
  int tid = threadIdx.x;
  u32 orig = blockIdx.y * gridDim.x + blockIdx.x;
  u32 xcd = orig & 7;
  u32 c = orig >> 3;                       // [0, 8*gridDim.x)
  int m0 = (int)(xcd * 8 + (c & 7)) * 128; // m-row in [0,64)
  int n0 = (int)(c >> 3) * 128;            // n-col in [0,gridDim.x)
  int w = tid >> 6, l = tid & 63;
  int wr = w >> 1, wc = w & 1;
  int lr = l & 15, lg = l >> 4;
  int rloc = l >> 3, cc = l & 7;
  int scc8 = (cc ^ rloc) * 8;

  f32x4 acc[4][4];
#pragma unroll
  for (int i = 0; i < 4; i++)
#pragma unroll
    for (int j = 0; j < 4; j++) acc[i][j] = (f32x4)0.0f;

  for (int kt = 0; kt < K; kt += 64) {
    __syncthreads();
#pragma unroll
    for (int qq = 0; qq < 4; ++qq) {
      int row = 32 * w + 8 * qq + rloc;
      gl_lds16(A + (size_t)(m0 + row) * K + kt + scc8, &As[(32 * w + 8 * qq) * 64]);
      gl_lds16(Bt + (size_t)(n0 + row) * K + kt + scc8, &Bs[(32 * w + 8 * qq) * 64]);
    }
    __syncthreads();
#pragma unroll
    for (int kk = 0; kk < 2; ++kk) {
      bf16x8 af[4], bfr[4];
#pragma unroll
      for (int i = 0; i < 4; i++)
        af[i] = load_frag16(swz(As, wr * 64 + i * 16 + lr, kk * 64 + lg * 16));
#pragma unroll
      for (int j = 0; j < 4; j++)
        bfr[j] = load_frag16(swz(Bs, wc * 64 + j * 16 + lr, kk * 64 + lg * 16));
#pragma unroll
      for (int i = 0; i < 4; i++)
#pragma unroll
        for (int j = 0; j < 4; j++)
          acc[i][j] = __builtin_amdgcn_mfma_f32_16x16x32_bf16(af[i], bfr[j], acc[i][j], 0, 0, 0);
    }
  }

  if (MODE == 0) {
#pragma unroll
    for (int i = 0; i < 4; i++) {
#pragma unroll
      for (int j = 0; j < 4; j++) {
        int col = n0 + wc * 64 + j * 16 + lr;
        float bv = bias[col];
#pragma unroll
        for (int r = 0; r < 4; r++) {
          int row = m0 + wr * 64 + i * 16 + lg * 4 + r;
          ((float*)Cout)[(size_t)row * N + col] = acc[i][j][r] + bv;
        }
      }
    }
  } else {
    if (n0 < 2048) {
      // Q|K slice -> qkb bf16, row stride 2048
#pragma unroll
      for (int i = 0; i < 4; i++) {
#pragma unroll
        for (int j = 0; j < 4; j++) {
          int col = n0 + wc * 64 + j * 16 + lr;
          float bv = bias[col];
#pragma unroll
          for (int r = 0; r < 4; r++) {
            int row = m0 + wr * 64 + i * 16 + lg * 4 + r;
            ((u16*)Cout)[(size_t)row * 2048 + col] = f32_to_bf16(acc[i][j][r] + bv);
          }
        }
      }
    } else {
      // V slice -> vTg[bh][64][2048] transposed; 4 consecutive l per lane = 8B chunk
#pragma unroll
      for (int i = 0; i < 4; i++) {
        int row0 = m0 + wr * 64 + i * 16 + lg * 4;
        int bq = row0 >> 11;
        int l0 = row0 & 2047;
#pragma unroll
        for (int j = 0; j < 4; j++) {
          int col = n0 + wc * 64 + j * 16 + lr;
          float bv = bias[col];
          int d = col - 2048;
          int h = d >> 6, hd = d & 63;
          uint2 pk;
          pk.x = cvt_pk_bf16(acc[i][j][0] + bv, acc[i][j][1] + bv);
          pk.y = cvt_pk_bf16(acc[i][j][2] + bv, acc[i][j][3] + bv);
          *(uint2*)(vTg + ((size_t)(bq * 16 + h) * 64 + hd) * 2048 + l0) = pk;
        }
      }
    }
  }
}

// ---------------- causal flash attention (round-9 passing version, FROZEN) ----------------
// qkb: [B*L][2048] bf16 (Q|K). vTg: [bh][64][2048] bf16. attnb: [B*L][1024] bf16.
// 256 threads (4 waves), 128 q-rows per block. grid (8, 64), XCD-swizzled so
// all 8 q-blocks of one (b,h) share an XCD's L2. K and V staged 128 rows per
// phase (two 64x64 swizzled sub-tiles each), double-buffered.
__global__ __launch_bounds__(256, 2) void attn_kernel(
    const u16* __restrict__ qkb, const u16* __restrict__ vTg,
    u16* __restrict__ attnb) {
  __shared__ __attribute__((aligned(16))) u16 Ks[2][2 * 64 * 64];
  __shared__ __attribute__((aligned(16))) u16 Vt[2][2 * 64 * 64];
  __shared__ __attribute__((aligned(16))) u16 Pl[4][32 * 64];
  int tid = threadIdx.x;
  int w = tid >> 6, l = tid & 63;
  int lr = l & 15, lg = l >> 4;
  int rloc = l >> 3, cc = l & 7;
  int scc8 = (cc ^ rloc) * 8;
  u32 orig = blockIdx.y * 8 + blockIdx.x;
  u32 wg = (orig & 7) * 64 + (orig >> 3);
  int bx = wg & 7;
  int bh = wg >> 3;
  int b = bh >> 4, h = bh & 15;
  const u16* base = qkb + (size_t)b * 2048 * 2048;
  const u16* kglob = base + 1024 + h * 64;
  const u16* vbase = vTg + (size_t)bh * 64 * 2048;
  u16* PlW = Pl[w];
  int usub = w >> 1, wl = w & 1;
  const float SCALE = 0.18033688011112042f;  // 0.125 * log2(e)

#define STAGE128(bi, tt)                                                        \
  do {                                                                          \
    int kv0_ = (tt) * 128;                                                      \
    _Pragma("unroll")                                                           \
    for (int qq = 0; qq < 4; ++qq) {                                            \
      int lrow_ = 32 * wl + 8 * qq;                                             \
      gl_lds16(kglob + (size_t)(kv0_ + usub * 64 + lrow_ + rloc) * 2048 + scc8, \
               &Ks[bi][usub * 4096 + lrow_ * 64]);                              \
      gl_lds16(vbase + (size_t)(lrow_ + rloc) * 2048 + kv0_ + usub * 64 + scc8, \
               &Vt[bi][usub * 4096 + lrow_ * 64]);                              \
    }                                                                           \
  } while (0)

  for (int half = 0; half < 2; ++half) {
    int s = half ? 15 - bx : bx;
    int qb = s * 128;
    int nst = s + 1;
    int tmax64 = 2 * s + (w >> 1);

    bf16x8 qf[2][2];
#pragma unroll
    for (int i = 0; i < 2; i++)
#pragma unroll
      for (int kk = 0; kk < 2; kk++) {
        int row = qb + w * 32 + i * 16 + lr;
        uint4 v = *(const uint4*)(base + (size_t)row * 2048 + h * 64 + kk * 32 + lg * 8);
        u32 wd[4] = {v.x, v.y, v.z, v.w};
#pragma unroll
        for (int e = 0; e < 4; e++) {
          float flo = bf16_to_f32((u16)(wd[e] & 0xFFFFu)) * SCALE;
          float fhi = bf16_to_f32((u16)(wd[e] >> 16)) * SCALE;
          wd[e] = cvt_pk_bf16(flo, fhi);
        }
        uint4 sv; sv.x = wd[0]; sv.y = wd[1]; sv.z = wd[2]; sv.w = wd[3];
        qf[i][kk] = __builtin_bit_cast(bf16x8, sv);
      }

    float m_st[2] = {-1e30f, -1e30f};
    float l_st[2] = {0.f, 0.f};
    f32x4 of[2][4];
#pragma unroll
    for (int i = 0; i < 2; i++)
#pragma unroll
      for (int j = 0; j < 4; j++) of[i][j] = (f32x4)0.0f;

    STAGE128(0, 0);

    for (int t = 0; t < nst; ++t) {
      int cur = t & 1;
      __syncthreads();  // staged data for t arrived; all waves done with buf cur
      if (t + 1 < nst) STAGE128(cur ^ 1, t + 1);

#pragma unroll
      for (int u = 0; u < 2; ++u) {
        int t64 = 2 * t + u;
        if (t64 <= tmax64) {
          const u16* Kb = Ks[cur] + u * 4096;
          const u16* Vb = Vt[cur] + u * 4096;

          f32x4 St[4][2];
#pragma unroll
          for (int j = 0; j < 4; j++)
#pragma unroll
            for (int i = 0; i < 2; i++) St[j][i] = (f32x4)0.0f;
          __builtin_amdgcn_s_setprio(1);
#pragma unroll
          for (int kk = 0; kk < 2; ++kk) {
            bf16x8 kbf[4];
#pragma unroll
            for (int j = 0; j < 4; j++)
              kbf[j] = load_frag16(swz(Kb, j * 16 + lr, kk * 64 + lg * 16));
#pragma unroll
            for (int j = 0; j < 4; j++)
#pragma unroll
              for (int i = 0; i < 2; i++)
                St[j][i] = __builtin_amdgcn_mfma_f32_16x16x32_bf16(kbf[j], qf[i][kk], St[j][i], 0, 0, 0);
          }
          __builtin_amdgcn_s_setprio(0);

          if (t64 == tmax64) {  // diagonal tile: mask k > q
#pragma unroll
            for (int j = 0; j < 4; j++)
#pragma unroll
              for (int i = 0; i < 2; i++)
#pragma unroll
                for (int r = 0; r < 4; r++) {
                  int kabs = t64 * 64 + j * 16 + lg * 4 + r;
                  int qabs = qb + w * 32 + i * 16 + lr;
                  if (kabs > qabs) St[j][i][r] = -1e30f;
                }
          }

          // lane-local online softmax (log2 domain), defer-max THR=10
#pragma unroll
          for (int i = 0; i < 2; ++i) {
            float tj[4];
#pragma unroll
            for (int j = 0; j < 4; j++)
              tj[j] = fmaxf(fmaxf(St[j][i][0], St[j][i][1]),
                            fmaxf(St[j][i][2], St[j][i][3]));
            float tm = fmaxf(fmaxf(tj[0], tj[1]), fmaxf(tj[2], tj[3]));
            tm = fmaxf(tm, __shfl_xor(tm, 16));
            tm = fmaxf(tm, __shfl_xor(tm, 32));
            if (!__all((int)(tm <= m_st[i] + 10.0f))) {
              float mn = fmaxf(m_st[i], tm);
              float fsc = exp2_fast(m_st[i] - mn);
              m_st[i] = mn;
              l_st[i] *= fsc;
#pragma unroll
              for (int r = 0; r < 4; ++r) {
                float ff = __shfl(fsc, lg * 4 + r);
#pragma unroll
                for (int jd = 0; jd < 4; jd++) of[i][jd][r] *= ff;
              }
            }
            float rj[4];
#pragma unroll
            for (int j = 0; j < 4; ++j) {
              float p0 = exp2_fast(St[j][i][0] - m_st[i]);
              float p1 = exp2_fast(St[j][i][1] - m_st[i]);
              float p2 = exp2_fast(St[j][i][2] - m_st[i]);
              float p3 = exp2_fast(St[j][i][3] - m_st[i]);
              rj[j] = (p0 + p1) + (p2 + p3);
              uint2 pk;
              pk.x = cvt_pk_bf16(p0, p1);
              pk.y = cvt_pk_bf16(p2, p3);
              *(uint2*)swzw(PlW, i * 16 + lr, j * 32 + lg * 8) = pk;
            }
            float rs = (rj[0] + rj[1]) + (rj[2] + rj[3]);
            rs += __shfl_xor(rs, 16);
            rs += __shfl_xor(rs, 32);
            l_st[i] += rs;
          }

          // PV: O[q][d] += P[q][k] * V[k][d]
          __builtin_amdgcn_s_setprio(1);
#pragma unroll
          for (int ks = 0; ks < 2; ++ks) {
            bf16x8 ap[2], vbf[4];
#pragma unroll
            for (int i = 0; i < 2; i++)
              ap[i] = load_frag16(swz(PlW, i * 16 + lr, ks * 64 + lg * 16));
#pragma unroll
            for (int jd = 0; jd < 4; jd++)
              vbf[jd] = load_frag16(swz(Vb, jd * 16 + lr, ks * 64 + lg * 16));
#pragma unroll
            for (int i = 0; i < 2; i++)
#pragma unroll
              for (int jd = 0; jd < 4; jd++)
                of[i][jd] = __builtin_amdgcn_mfma_f32_16x16x32_bf16(ap[i], vbf[jd], of[i][jd], 0, 0, 0);
          }
          __builtin_amdgcn_s_setprio(0);
        }
      }
    }
    __syncthreads();  // protect staging buffers before next half / exit

    // epilogue: O /= lsum, store bf16 head-merged
#pragma unroll
    for (int i = 0; i < 2; i++) {
#pragma unroll
      for (int r = 0; r < 4; r++) {
        float ls = __shfl(l_st[i], lg * 4 + r);
        float inv = 1.0f / ls;
#pragma unroll
        for (int jd = 0; jd < 4; jd++) {
          int row = qb + w * 32 + i * 16 + lg * 4 + r;
          int col = h * 64 + jd * 16 + lr;
          attnb[((size_t)b * 2048 + row) * 1024 + col] = f32_to_bf16(of[i][jd][r] * inv);
        }
      }
    }
  }
#undef STAGE128
}

extern "C" void kernel_launch(void* const* d_in, const int* in_sizes, int n_in,
                              void* d_out, int out_size, void* d_ws, size_t ws_size,
                              hipStream_t stream) {
  const float* x = (const float*)d_in[0];
  const float* Wqkv = (const float*)d_in[1];
  const float* bqkv = (const float*)d_in[2];
  const float* Wproj = (const float*)d_in[3];
  const float* bproj = (const float*)d_in[4];
  float* out = (float*)d_out;

  char* ws = (char*)d_ws;
  u16* xb    = (u16*)(ws);                 // 8192*1024*2 = 16,777,216
  u16* wqT   = (u16*)(ws + 16777216);      // 3072*1024*2 =  6,291,456
  u16* wpT   = (u16*)(ws + 23068672);      // 1024*1024*2 =  2,097,152
  u16* qkb   = (u16*)(ws + 25165824);      // 8192*2048*2 = 33,554,432 (Q|K)
  u16* vTg   = (u16*)(ws + 58720256);      // 64*64*2048*2= 16,777,216
  u16* attnb = (u16*)(ws + 75497472);      // 8192*1024*2 = 16,777,216  (total ~92MB)

  cvt_f32_bf16<<<8192, 256, 0, stream>>>(x, xb, 8388608);
  transpose_cvt2<<<dim3(128, 32), 256, 0, stream>>>(Wqkv, wqT, Wproj, wpT);
  gemm_bf16<2><<<dim3(24, 64), 256, 0, stream>>>(xb, wqT, bqkv, (void*)qkb, 8192, 3072, 1024, vTg);
  attn_kernel<<<dim3(8, 64), 256, 0, stream>>>(qkb, vTg, attnb);
  gemm_bf16<0><<<dim3(8, 64), 256, 0, stream>>>(attnb, wpT, bproj, (void*)out, 8192, 1024, 1024, nullptr);
}

// Round 13
// 154.243 us; speedup vs baseline: 1.0408x; 1.0126x over previous
//
#include <hip/hip_runtime.h>
#include <stdint.h>

#define DEV __device__ __forceinline__

typedef uint32_t u32;
typedef uint16_t u16;
typedef __attribute__((ext_vector_type(4))) float f32x4;
typedef __attribute__((ext_vector_type(8))) __bf16 bf16x8;

DEV u16 f32_to_bf16(float f) {
  u32 u = __builtin_bit_cast(u32, f);
  u += 0x7FFFu + ((u >> 16) & 1u);
  return (u16)(u >> 16);
}
DEV float bf16_to_f32(u16 h) {
  u32 u = ((u32)h) << 16;
  return __builtin_bit_cast(float, u);
}
DEV bf16x8 load_frag16(const u16* p) {
  return __builtin_bit_cast(bf16x8, *(const uint4*)p);
}
DEV float exp2_fast(float x) {
#if __has_builtin(__builtin_amdgcn_exp2f)
  return __builtin_amdgcn_exp2f(x);
#else
  float r;
  asm("v_exp_f32 %0, %1\n\ts_nop 0" : "=v"(r) : "v"(x));
  return r;
#endif
}
DEV u32 cvt_pk_bf16(float lo, float hi) {
  u32 r;
  asm("v_cvt_pk_bf16_f32 %0, %1, %2" : "=v"(r) : "v"(lo), "v"(hi));
  return r;
}

// global -> LDS direct (16B per lane, dest = wave-uniform base + lane*16)
DEV void gl_lds16(const u16* g, u16* l) {
  __builtin_amdgcn_global_load_lds(
      (__attribute__((address_space(1))) void*)(u16*)g,
      (__attribute__((address_space(3))) void*)l, 16, 0, 0);
}

// XOR-swizzled address into a [rows][64 bf16] tile (128 B rows).
DEV const u16* swz(const u16* basep, int row, int colByte) {
  return (const u16*)((const char*)basep + row * 128 + (colByte ^ ((row & 7) << 4)));
}
DEV u16* swzw(u16* basep, int row, int colByte) {
  return (u16*)((char*)basep + row * 128 + (colByte ^ ((row & 7) << 4)));
}

// ------ prep: weight transposes + x fp32->bf16 conversion, one launch ------
// grid (384, 32), 256 thr:
//   x<96   : Wqkv [1024][3072] -> wqT [3072][1024]
//   96-127 : Wproj [1024][1024] -> wpT [1024][1024]
//   x>=128 : cvt chunk id = (x-128) + 256*y, 1024 elems each (8192 total)
__global__ void prep_kernel(const float* __restrict__ inA, u16* __restrict__ outA,
                            const float* __restrict__ inB, u16* __restrict__ outB,
                            const float* __restrict__ x, u16* __restrict__ xb) {
  __shared__ float tile[32][33];
  if (blockIdx.x >= 128) {
    int id = (blockIdx.x - 128) + 256 * blockIdx.y;
    int i = (id * 256 + threadIdx.x) * 4;
    float4 v = *(const float4*)(x + i);
    ushort4 o;
    o.x = f32_to_bf16(v.x); o.y = f32_to_bf16(v.y);
    o.z = f32_to_bf16(v.z); o.w = f32_to_bf16(v.w);
    *(ushort4*)(xb + i) = o;
    return;
  }
  const float* in; u16* out; int C; int bxi;
  if (blockIdx.x < 96) { in = inA; out = outA; C = 3072; bxi = blockIdx.x; }
  else { in = inB; out = outB; C = 1024; bxi = blockIdx.x - 96; }
  const int R = 1024;
  int bx = bxi * 32;
  int by = blockIdx.y * 32;
  int tx = threadIdx.x & 31;
  int ty = threadIdx.x >> 5;
#pragma unroll
  for (int i = 0; i < 32; i += 8)
    tile[ty + i][tx] = in[(size_t)(by + ty + i) * C + bx + tx];
  __syncthreads();
#pragma unroll
  for (int i = 0; i < 32; i += 8)
    out[(size_t)(bx + ty + i) * R + by + tx] = f32_to_bf16(tile[tx][ty + i]);
}

// ---------------- bf16 GEMM 128x128: C = A * Bt^T + bias ----------------
// MODE 0: C = float [M][N].
// MODE 2: QKV-fused. Columns <2048 (Q|K) -> bf16 qkb with row stride 2048.
//         Columns >=2048 (V) -> written TRANSPOSED into vTg[bh][64][2048].
// Block mapping: XCD chunk (orig&7) then M-FASTEST within the chunk.
template <int MODE>
__global__ __launch_bounds__(256, 2) void gemm_bf16(
    const u16* __restrict__ A, const u16* __restrict__ Bt,
    const float* __restrict__ bias, void* __restrict__ Cout,
    int M, int N, int K, u16* __restrict__ vTg) {
  __shared__ __attribute__((aligned(16))) u16 As[128 * 64];
  __shared__ __attribute__((aligned(16))) u16 Bs[128 * 64];
  int tid = threadIdx.x;
  u32 orig = blockIdx.y * gridDim.x + blockIdx.x;
  u32 xcd = orig & 7;
  u32 c = orig >> 3;                       // [0, 8*gridDim.x)
  int m0 = (int)(xcd * 8 + (c & 7)) * 128; // m-row in [0,64)
  int n0 = (int)(c >> 3) * 128;            // n-col in [0,gridDim.x)
  int w = tid >> 6, l = tid & 63;
  int wr = w >> 1, wc = w & 1;
  int lr = l & 15, lg = l >> 4;
  int rloc = l >> 3, cc = l & 7;
  int scc8 = (cc ^ rloc) * 8;

  f32x4 acc[4][4];
#pragma unroll
  for (int i = 0; i < 4; i++)
#pragma unroll
    for (int j = 0; j < 4; j++) acc[i][j] = (f32x4)0.0f;

  for (int kt = 0; kt < K; kt += 64) {
    __syncthreads();
#pragma unroll
    for (int qq = 0; qq < 4; ++qq) {
      int row = 32 * w + 8 * qq + rloc;
      gl_lds16(A + (size_t)(m0 + row) * K + kt + scc8, &As[(32 * w + 8 * qq) * 64]);
      gl_lds16(Bt + (size_t)(n0 + row) * K + kt + scc8, &Bs[(32 * w + 8 * qq) * 64]);
    }
    __syncthreads();
#pragma unroll
    for (int kk = 0; kk < 2; ++kk) {
      bf16x8 af[4], bfr[4];
#pragma unroll
      for (int i = 0; i < 4; i++)
        af[i] = load_frag16(swz(As, wr * 64 + i * 16 + lr, kk * 64 + lg * 16));
#pragma unroll
      for (int j = 0; j < 4; j++)
        bfr[j] = load_frag16(swz(Bs, wc * 64 + j * 16 + lr, kk * 64 + lg * 16));
#pragma unroll
      for (int i = 0; i < 4; i++)
#pragma unroll
        for (int j = 0; j < 4; j++)
          acc[i][j] = __builtin_amdgcn_mfma_f32_16x16x32_bf16(af[i], bfr[j], acc[i][j], 0, 0, 0);
    }
  }

  if (MODE == 0) {
#pragma unroll
    for (int i = 0; i < 4; i++) {
#pragma unroll
      for (int j = 0; j < 4; j++) {
        int col = n0 + wc * 64 + j * 16 + lr;
        float bv = bias[col];
#pragma unroll
        for (int r = 0; r < 4; r++) {
          int row = m0 + wr * 64 + i * 16 + lg * 4 + r;
          ((float*)Cout)[(size_t)row * N + col] = acc[i][j][r] + bv;
        }
      }
    }
  } else {
    if (n0 < 2048) {
      // Q|K slice -> qkb bf16, row stride 2048
#pragma unroll
      for (int i = 0; i < 4; i++) {
#pragma unroll
        for (int j = 0; j < 4; j++) {
          int col = n0 + wc * 64 + j * 16 + lr;
          float bv = bias[col];
#pragma unroll
          for (int r = 0; r < 4; r++) {
            int row = m0 + wr * 64 + i * 16 + lg * 4 + r;
            ((u16*)Cout)[(size_t)row * 2048 + col] = f32_to_bf16(acc[i][j][r] + bv);
          }
        }
      }
    } else {
      // V slice -> vTg[bh][64][2048] transposed; 4 consecutive l per lane = 8B chunk
#pragma unroll
      for (int i = 0; i < 4; i++) {
        int row0 = m0 + wr * 64 + i * 16 + lg * 4;
        int bq = row0 >> 11;
        int l0 = row0 & 2047;
#pragma unroll
        for (int j = 0; j < 4; j++) {
          int col = n0 + wc * 64 + j * 16 + lr;
          float bv = bias[col];
          int d = col - 2048;
          int h = d >> 6, hd = d & 63;
          uint2 pk;
          pk.x = cvt_pk_bf16(acc[i][j][0] + bv, acc[i][j][1] + bv);
          pk.y = cvt_pk_bf16(acc[i][j][2] + bv, acc[i][j][3] + bv);
          *(uint2*)(vTg + ((size_t)(bq * 16 + h) * 64 + hd) * 2048 + l0) = pk;
        }
      }
    }
  }
}

// ---------------- causal flash attention (round-11 passing version, FROZEN) ----------------
// qkb: [B*L][2048] bf16 (Q|K). vTg: [bh][64][2048] bf16. attnb: [B*L][1024] bf16.
// 256 threads (4 waves), 128 q-rows per block. grid (8, 64), XCD-swizzled so
// all 8 q-blocks of one (b,h) share an XCD's L2. K and V staged 128 rows per
// phase (two 64x64 swizzled sub-tiles each), double-buffered.
__global__ __launch_bounds__(256, 2) void attn_kernel(
    const u16* __restrict__ qkb, const u16* __restrict__ vTg,
    u16* __restrict__ attnb) {
  __shared__ __attribute__((aligned(16))) u16 Ks[2][2 * 64 * 64];
  __shared__ __attribute__((aligned(16))) u16 Vt[2][2 * 64 * 64];
  __shared__ __attribute__((aligned(16))) u16 Pl[4][32 * 64];
  int tid = threadIdx.x;
  int w = tid >> 6, l = tid & 63;
  int lr = l & 15, lg = l >> 4;
  int rloc = l >> 3, cc = l & 7;
  int scc8 = (cc ^ rloc) * 8;
  u32 orig = blockIdx.y * 8 + blockIdx.x;
  u32 wg = (orig & 7) * 64 + (orig >> 3);
  int bx = wg & 7;
  int bh = wg >> 3;
  int b = bh >> 4, h = bh & 15;
  const u16* base = qkb + (size_t)b * 2048 * 2048;
  const u16* kglob = base + 1024 + h * 64;
  const u16* vbase = vTg + (size_t)bh * 64 * 2048;
  u16* PlW = Pl[w];
  int usub = w >> 1, wl = w & 1;
  const float SCALE = 0.18033688011112042f;  // 0.125 * log2(e)

#define STAGE128(bi, tt)                                                        \
  do {                                                                          \
    int kv0_ = (tt) * 128;                                                      \
    _Pragma("unroll")                                                           \
    for (int qq = 0; qq < 4; ++qq) {                                            \
      int lrow_ = 32 * wl + 8 * qq;                                             \
      gl_lds16(kglob + (size_t)(kv0_ + usub * 64 + lrow_ + rloc) * 2048 + scc8, \
               &Ks[bi][usub * 4096 + lrow_ * 64]);                              \
      gl_lds16(vbase + (size_t)(lrow_ + rloc) * 2048 + kv0_ + usub * 64 + scc8, \
               &Vt[bi][usub * 4096 + lrow_ * 64]);                              \
    }                                                                           \
  } while (0)

  for (int half = 0; half < 2; ++half) {
    int s = half ? 15 - bx : bx;
    int qb = s * 128;
    int nst = s + 1;
    int tmax64 = 2 * s + (w >> 1);

    bf16x8 qf[2][2];
#pragma unroll
    for (int i = 0; i < 2; i++)
#pragma unroll
      for (int kk = 0; kk < 2; kk++) {
        int row = qb + w * 32 + i * 16 + lr;
        uint4 v = *(const uint4*)(base + (size_t)row * 2048 + h * 64 + kk * 32 + lg * 8);
        u32 wd[4] = {v.x, v.y, v.z, v.w};
#pragma unroll
        for (int e = 0; e < 4; e++) {
          float flo = bf16_to_f32((u16)(wd[e] & 0xFFFFu)) * SCALE;
          float fhi = bf16_to_f32((u16)(wd[e] >> 16)) * SCALE;
          wd[e] = cvt_pk_bf16(flo, fhi);
        }
        uint4 sv; sv.x = wd[0]; sv.y = wd[1]; sv.z = wd[2]; sv.w = wd[3];
        qf[i][kk] = __builtin_bit_cast(bf16x8, sv);
      }

    float m_st[2] = {-1e30f, -1e30f};
    float l_st[2] = {0.f, 0.f};
    f32x4 of[2][4];
#pragma unroll
    for (int i = 0; i < 2; i++)
#pragma unroll
      for (int j = 0; j < 4; j++) of[i][j] = (f32x4)0.0f;

    STAGE128(0, 0);

    for (int t = 0; t < nst; ++t) {
      int cur = t & 1;
      __syncthreads();  // staged data for t arrived; all waves done with buf cur
      if (t + 1 < nst) STAGE128(cur ^ 1, t + 1);

#pragma unroll
      for (int u = 0; u < 2; ++u) {
        int t64 = 2 * t + u;
        if (t64 <= tmax64) {
          const u16* Kb = Ks[cur] + u * 4096;
          const u16* Vb = Vt[cur] + u * 4096;

          f32x4 St[4][2];
#pragma unroll
          for (int j = 0; j < 4; j++)
#pragma unroll
            for (int i = 0; i < 2; i++) St[j][i] = (f32x4)0.0f;
          __builtin_amdgcn_s_setprio(1);
#pragma unroll
          for (int kk = 0; kk < 2; ++kk) {
            bf16x8 kbf[4];
#pragma unroll
            for (int j = 0; j < 4; j++)
              kbf[j] = load_frag16(swz(Kb, j * 16 + lr, kk * 64 + lg * 16));
#pragma unroll
            for (int j = 0; j < 4; j++)
#pragma unroll
              for (int i = 0; i < 2; i++)
                St[j][i] = __builtin_amdgcn_mfma_f32_16x16x32_bf16(kbf[j], qf[i][kk], St[j][i], 0, 0, 0);
          }
          __builtin_amdgcn_s_setprio(0);

          if (t64 == tmax64) {  // diagonal tile: mask k > q
#pragma unroll
            for (int j = 0; j < 4; j++)
#pragma unroll
              for (int i = 0; i < 2; i++)
#pragma unroll
                for (int r = 0; r < 4; r++) {
                  int kabs = t64 * 64 + j * 16 + lg * 4 + r;
                  int qabs = qb + w * 32 + i * 16 + lr;
                  if (kabs > qabs) St[j][i][r] = -1e30f;
                }
          }

          // lane-local online softmax (log2 domain), defer-max THR=10
#pragma unroll
          for (int i = 0; i < 2; ++i) {
            float tj[4];
#pragma unroll
            for (int j = 0; j < 4; j++)
              tj[j] = fmaxf(fmaxf(St[j][i][0], St[j][i][1]),
                            fmaxf(St[j][i][2], St[j][i][3]));
            float tm = fmaxf(fmaxf(tj[0], tj[1]), fmaxf(tj[2], tj[3]));
            tm = fmaxf(tm, __shfl_xor(tm, 16));
            tm = fmaxf(tm, __shfl_xor(tm, 32));
            if (!__all((int)(tm <= m_st[i] + 10.0f))) {
              float mn = fmaxf(m_st[i], tm);
              float fsc = exp2_fast(m_st[i] - mn);
              m_st[i] = mn;
              l_st[i] *= fsc;
#pragma unroll
              for (int r = 0; r < 4; ++r) {
                float ff = __shfl(fsc, lg * 4 + r);
#pragma unroll
                for (int jd = 0; jd < 4; jd++) of[i][jd][r] *= ff;
              }
            }
            float rj[4];
#pragma unroll
            for (int j = 0; j < 4; ++j) {
              float p0 = exp2_fast(St[j][i][0] - m_st[i]);
              float p1 = exp2_fast(St[j][i][1] - m_st[i]);
              float p2 = exp2_fast(St[j][i][2] - m_st[i]);
              float p3 = exp2_fast(St[j][i][3] - m_st[i]);
              rj[j] = (p0 + p1) + (p2 + p3);
              uint2 pk;
              pk.x = cvt_pk_bf16(p0, p1);
              pk.y = cvt_pk_bf16(p2, p3);
              *(uint2*)swzw(PlW, i * 16 + lr, j * 32 + lg * 8) = pk;
            }
            float rs = (rj[0] + rj[1]) + (rj[2] + rj[3]);
            rs += __shfl_xor(rs, 16);
            rs += __shfl_xor(rs, 32);
            l_st[i] += rs;
          }

          // PV: O[q][d] += P[q][k] * V[k][d]
          __builtin_amdgcn_s_setprio(1);
#pragma unroll
          for (int ks = 0; ks < 2; ++ks) {
            bf16x8 ap[2], vbf[4];
#pragma unroll
            for (int i = 0; i < 2; i++)
              ap[i] = load_frag16(swz(PlW, i * 16 + lr, ks * 64 + lg * 16));
#pragma unroll
            for (int jd = 0; jd < 4; jd++)
              vbf[jd] = load_frag16(swz(Vb, jd * 16 + lr, ks * 64 + lg * 16));
#pragma unroll
            for (int i = 0; i < 2; i++)
#pragma unroll
              for (int jd = 0; jd < 4; jd++)
                of[i][jd] = __builtin_amdgcn_mfma_f32_16x16x32_bf16(ap[i], vbf[jd], of[i][jd], 0, 0, 0);
          }
          __builtin_amdgcn_s_setprio(0);
        }
      }
    }
    __syncthreads();  // protect staging buffers before next half / exit

    // epilogue: O /= lsum, store bf16 head-merged
#pragma unroll
    for (int i = 0; i < 2; i++) {
#pragma unroll
      for (int r = 0; r < 4; r++) {
        float ls = __shfl(l_st[i], lg * 4 + r);
        float inv = 1.0f / ls;
#pragma unroll
        for (int jd = 0; jd < 4; jd++) {
          int row = qb + w * 32 + i * 16 + lg * 4 + r;
          int col = h * 64 + jd * 16 + lr;
          attnb[((size_t)b * 2048 + row) * 1024 + col] = f32_to_bf16(of[i][jd][r] * inv);
        }
      }
    }
  }
#undef STAGE128
}

extern "C" void kernel_launch(void* const* d_in, const int* in_sizes, int n_in,
                              void* d_out, int out_size, void* d_ws, size_t ws_size,
                              hipStream_t stream) {
  const float* x = (const float*)d_in[0];
  const float* Wqkv = (const float*)d_in[1];
  const float* bqkv = (const float*)d_in[2];
  const float* Wproj = (const float*)d_in[3];
  const float* bproj = (const float*)d_in[4];
  float* out = (float*)d_out;

  char* ws = (char*)d_ws;
  u16* xb    = (u16*)(ws);                 // 8192*1024*2 = 16,777,216
  u16* wqT   = (u16*)(ws + 16777216);      // 3072*1024*2 =  6,291,456
  u16* wpT   = (u16*)(ws + 23068672);      // 1024*1024*2 =  2,097,152
  u16* qkb   = (u16*)(ws + 25165824);      // 8192*2048*2 = 33,554,432 (Q|K)
  u16* vTg   = (u16*)(ws + 58720256);      // 64*64*2048*2= 16,777,216
  u16* attnb = (u16*)(ws + 75497472);      // 8192*1024*2 = 16,777,216  (total ~92MB)

  prep_kernel<<<dim3(384, 32), 256, 0, stream>>>(Wqkv, wqT, Wproj, wpT, x, xb);
  gemm_bf16<2><<<dim3(24, 64), 256, 0, stream>>>(xb, wqT, bqkv, (void*)qkb, 8192, 3072, 1024, vTg);
  attn_kernel<<<dim3(8, 64), 256, 0, stream>>>(qkb, vTg, attnb);
  gemm_bf16<0><<<dim3(8, 64), 256, 0, stream>>>(attnb, wpT, bproj, (void*)out, 8192, 1024, 1024, nullptr);
}

// Round 14
// 154.212 us; speedup vs baseline: 1.0410x; 1.0002x over previous
//
#include <hip/hip_runtime.h>
#include <stdint.h>

#define DEV __device__ __forceinline__

typedef uint32_t u32;
typedef uint16_t u16;
typedef __attribute__((ext_vector_type(4))) float f32x4;
typedef __attribute__((ext_vector_type(8))) __bf16 bf16x8;

DEV u16 f32_to_bf16(float f) {
  u32 u = __builtin_bit_cast(u32, f);
  u += 0x7FFFu + ((u >> 16) & 1u);
  return (u16)(u >> 16);
}
DEV float bf16_to_f32(u16 h) {
  u32 u = ((u32)h) << 16;
  return __builtin_bit_cast(float, u);
}
DEV bf16x8 load_frag16(const u16* p) {
  return __builtin_bit_cast(bf16x8, *(const uint4*)p);
}
DEV float exp2_fast(float x) {
#if __has_builtin(__builtin_amdgcn_exp2f)
  return __builtin_amdgcn_exp2f(x);
#else
  float r;
  asm("v_exp_f32 %0, %1\n\ts_nop 0" : "=v"(r) : "v"(x));
  return r;
#endif
}
DEV u32 cvt_pk_bf16(float lo, float hi) {
  u32 r;
  asm("v_cvt_pk_bf16_f32 %0, %1, %2" : "=v"(r) : "v"(lo), "v"(hi));
  return r;
}

// global -> LDS direct (16B per lane, dest = wave-uniform base + lane*16)
DEV void gl_lds16(const u16* g, u16* l) {
  __builtin_amdgcn_global_load_lds(
      (__attribute__((address_space(1))) void*)(u16*)g,
      (__attribute__((address_space(3))) void*)l, 16, 0, 0);
}

// XOR-swizzled address into a [rows][64 bf16] tile (128 B rows).
DEV const u16* swz(const u16* basep, int row, int colByte) {
  return (const u16*)((const char*)basep + row * 128 + (colByte ^ ((row & 7) << 4)));
}
DEV u16* swzw(u16* basep, int row, int colByte) {
  return (u16*)((char*)basep + row * 128 + (colByte ^ ((row & 7) << 4)));
}

// ------ prep: weight transposes + x fp32->bf16 conversion, one launch ------
// grid (384, 32), 256 thr:
//   x<96   : Wqkv [1024][3072] -> wqT [3072][1024]
//   96-127 : Wproj [1024][1024] -> wpT [1024][1024]
//   x>=128 : cvt chunk id = (x-128) + 256*y, 1024 elems each (8192 total)
__global__ void prep_kernel(const float* __restrict__ inA, u16* __restrict__ outA,
                            const float* __restrict__ inB, u16* __restrict__ outB,
                            const float* __restrict__ x, u16* __restrict__ xb) {
  __shared__ float tile[32][33];
  if (blockIdx.x >= 128) {
    int id = (blockIdx.x - 128) + 256 * blockIdx.y;
    int i = (id * 256 + threadIdx.x) * 4;
    float4 v = *(const float4*)(x + i);
    ushort4 o;
    o.x = f32_to_bf16(v.x); o.y = f32_to_bf16(v.y);
    o.z = f32_to_bf16(v.z); o.w = f32_to_bf16(v.w);
    *(ushort4*)(xb + i) = o;
    return;
  }
  const float* in; u16* out; int C; int bxi;
  if (blockIdx.x < 96) { in = inA; out = outA; C = 3072; bxi = blockIdx.x; }
  else { in = inB; out = outB; C = 1024; bxi = blockIdx.x - 96; }
  const int R = 1024;
  int bx = bxi * 32;
  int by = blockIdx.y * 32;
  int tx = threadIdx.x & 31;
  int ty = threadIdx.x >> 5;
#pragma unroll
  for (int i = 0; i < 32; i += 8)
    tile[ty + i][tx] = in[(size_t)(by + ty + i) * C + bx + tx];
  __syncthreads();
#pragma unroll
  for (int i = 0; i < 32; i += 8)
    out[(size_t)(bx + ty + i) * R + by + tx] = f32_to_bf16(tile[tx][ty + i]);
}

// ---------------- bf16 GEMM 128x128: C = A * Bt^T + bias ----------------
// MODE 0: C = float [M][N].
// MODE 2: QKV-fused. Columns <2048 (Q|K) -> bf16 qkb with row stride 2048.
//         Columns >=2048 (V) -> written TRANSPOSED into vTg[bh][64][2048].
// Block mapping: XCD chunk (orig&7) then M-FASTEST within the chunk.
// launch_bounds(256,3): cap VGPR at ~170 (m97's kernel used 164 for this
// structure) -> 3 blocks/CU so the per-K-step barrier drain overlaps with
// other resident blocks' compute.
template <int MODE>
__global__ __launch_bounds__(256, 3) void gemm_bf16(
    const u16* __restrict__ A, const u16* __restrict__ Bt,
    const float* __restrict__ bias, void* __restrict__ Cout,
    int M, int N, int K, u16* __restrict__ vTg) {
  __shared__ __attribute__((aligned(16))) u16 As[128 * 64];
  __shared__ __attribute__((aligned(16))) u16 Bs[128 * 64];
  int tid = threadIdx.x;
  u32 orig = blockIdx.y * gridDim.x + blockIdx.x;
  u32 xcd = orig & 7;
  u32 c = orig >> 3;                       // [0, 8*gridDim.x)
  int m0 = (int)(xcd * 8 + (c & 7)) * 128; // m-row in [0,64)
  int n0 = (int)(c >> 3) * 128;            // n-col in [0,gridDim.x)
  int w = tid >> 6, l = tid & 63;
  int wr = w >> 1, wc = w & 1;
  int lr = l & 15, lg = l >> 4;
  int rloc = l >> 3, cc = l & 7;
  int scc8 = (cc ^ rloc) * 8;

  f32x4 acc[4][4];
#pragma unroll
  for (int i = 0; i < 4; i++)
#pragma unroll
    for (int j = 0; j < 4; j++) acc[i][j] = (f32x4)0.0f;

  for (int kt = 0; kt < K; kt += 64) {
    __syncthreads();
#pragma unroll
    for (int qq = 0; qq < 4; ++qq) {
      int row = 32 * w + 8 * qq + rloc;
      gl_lds16(A + (size_t)(m0 + row) * K + kt + scc8, &As[(32 * w + 8 * qq) * 64]);
      gl_lds16(Bt + (size_t)(n0 + row) * K + kt + scc8, &Bs[(32 * w + 8 * qq) * 64]);
    }
    __syncthreads();
#pragma unroll
    for (int kk = 0; kk < 2; ++kk) {
      bf16x8 af[4], bfr[4];
#pragma unroll
      for (int i = 0; i < 4; i++)
        af[i] = load_frag16(swz(As, wr * 64 + i * 16 + lr, kk * 64 + lg * 16));
#pragma unroll
      for (int j = 0; j < 4; j++)
        bfr[j] = load_frag16(swz(Bs, wc * 64 + j * 16 + lr, kk * 64 + lg * 16));
#pragma unroll
      for (int i = 0; i < 4; i++)
#pragma unroll
        for (int j = 0; j < 4; j++)
          acc[i][j] = __builtin_amdgcn_mfma_f32_16x16x32_bf16(af[i], bfr[j], acc[i][j], 0, 0, 0);
    }
  }

  if (MODE == 0) {
#pragma unroll
    for (int i = 0; i < 4; i++) {
#pragma unroll
      for (int j = 0; j < 4; j++) {
        int col = n0 + wc * 64 + j * 16 + lr;
        float bv = bias[col];
#pragma unroll
        for (int r = 0; r < 4; r++) {
          int row = m0 + wr * 64 + i * 16 + lg * 4 + r;
          ((float*)Cout)[(size_t)row * N + col] = acc[i][j][r] + bv;
        }
      }
    }
  } else {
    if (n0 < 2048) {
      // Q|K slice -> qkb bf16, row stride 2048
#pragma unroll
      for (int i = 0; i < 4; i++) {
#pragma unroll
        for (int j = 0; j < 4; j++) {
          int col = n0 + wc * 64 + j * 16 + lr;
          float bv = bias[col];
#pragma unroll
          for (int r = 0; r < 4; r++) {
            int row = m0 + wr * 64 + i * 16 + lg * 4 + r;
            ((u16*)Cout)[(size_t)row * 2048 + col] = f32_to_bf16(acc[i][j][r] + bv);
          }
        }
      }
    } else {
      // V slice -> vTg[bh][64][2048] transposed; 4 consecutive l per lane = 8B chunk
#pragma unroll
      for (int i = 0; i < 4; i++) {
        int row0 = m0 + wr * 64 + i * 16 + lg * 4;
        int bq = row0 >> 11;
        int l0 = row0 & 2047;
#pragma unroll
        for (int j = 0; j < 4; j++) {
          int col = n0 + wc * 64 + j * 16 + lr;
          float bv = bias[col];
          int d = col - 2048;
          int h = d >> 6, hd = d & 63;
          uint2 pk;
          pk.x = cvt_pk_bf16(acc[i][j][0] + bv, acc[i][j][1] + bv);
          pk.y = cvt_pk_bf16(acc[i][j][2] + bv, acc[i][j][3] + bv);
          *(uint2*)(vTg + ((size_t)(bq * 16 + h) * 64 + hd) * 2048 + l0) = pk;
        }
      }
    }
  }
}

// ---------------- causal flash attention (round-11 passing version, FROZEN) ----------------
// qkb: [B*L][2048] bf16 (Q|K). vTg: [bh][64][2048] bf16. attnb: [B*L][1024] bf16.
// 256 threads (4 waves), 128 q-rows per block. grid (8, 64), XCD-swizzled so
// all 8 q-blocks of one (b,h) share an XCD's L2. K and V staged 128 rows per
// phase (two 64x64 swizzled sub-tiles each), double-buffered.
__global__ __launch_bounds__(256, 2) void attn_kernel(
    const u16* __restrict__ qkb, const u16* __restrict__ vTg,
    u16* __restrict__ attnb) {
  __shared__ __attribute__((aligned(16))) u16 Ks[2][2 * 64 * 64];
  __shared__ __attribute__((aligned(16))) u16 Vt[2][2 * 64 * 64];
  __shared__ __attribute__((aligned(16))) u16 Pl[4][32 * 64];
  int tid = threadIdx.x;
  int w = tid >> 6, l = tid & 63;
  int lr = l & 15, lg = l >> 4;
  int rloc = l >> 3, cc = l & 7;
  int scc8 = (cc ^ rloc) * 8;
  u32 orig = blockIdx.y * 8 + blockIdx.x;
  u32 wg = (orig & 7) * 64 + (orig >> 3);
  int bx = wg & 7;
  int bh = wg >> 3;
  int b = bh >> 4, h = bh & 15;
  const u16* base = qkb + (size_t)b * 2048 * 2048;
  const u16* kglob = base + 1024 + h * 64;
  const u16* vbase = vTg + (size_t)bh * 64 * 2048;
  u16* PlW = Pl[w];
  int usub = w >> 1, wl = w & 1;
  const float SCALE = 0.18033688011112042f;  // 0.125 * log2(e)

#define STAGE128(bi, tt)                                                        \
  do {                                                                          \
    int kv0_ = (tt) * 128;                                                      \
    _Pragma("unroll")                                                           \
    for (int qq = 0; qq < 4; ++qq) {                                            \
      int lrow_ = 32 * wl + 8 * qq;                                             \
      gl_lds16(kglob + (size_t)(kv0_ + usub * 64 + lrow_ + rloc) * 2048 + scc8, \
               &Ks[bi][usub * 4096 + lrow_ * 64]);                              \
      gl_lds16(vbase + (size_t)(lrow_ + rloc) * 2048 + kv0_ + usub * 64 + scc8, \
               &Vt[bi][usub * 4096 + lrow_ * 64]);                              \
    }                                                                           \
  } while (0)

  for (int half = 0; half < 2; ++half) {
    int s = half ? 15 - bx : bx;
    int qb = s * 128;
    int nst = s + 1;
    int tmax64 = 2 * s + (w >> 1);

    bf16x8 qf[2][2];
#pragma unroll
    for (int i = 0; i < 2; i++)
#pragma unroll
      for (int kk = 0; kk < 2; kk++) {
        int row = qb + w * 32 + i * 16 + lr;
        uint4 v = *(const uint4*)(base + (size_t)row * 2048 + h * 64 + kk * 32 + lg * 8);
        u32 wd[4] = {v.x, v.y, v.z, v.w};
#pragma unroll
        for (int e = 0; e < 4; e++) {
          float flo = bf16_to_f32((u16)(wd[e] & 0xFFFFu)) * SCALE;
          float fhi = bf16_to_f32((u16)(wd[e] >> 16)) * SCALE;
          wd[e] = cvt_pk_bf16(flo, fhi);
        }
        uint4 sv; sv.x = wd[0]; sv.y = wd[1]; sv.z = wd[2]; sv.w = wd[3];
        qf[i][kk] = __builtin_bit_cast(bf16x8, sv);
      }

    float m_st[2] = {-1e30f, -1e30f};
    float l_st[2] = {0.f, 0.f};
    f32x4 of[2][4];
#pragma unroll
    for (int i = 0; i < 2; i++)
#pragma unroll
      for (int j = 0; j < 4; j++) of[i][j] = (f32x4)0.0f;

    STAGE128(0, 0);

    for (int t = 0; t < nst; ++t) {
      int cur = t & 1;
      __syncthreads();  // staged data for t arrived; all waves done with buf cur
      if (t + 1 < nst) STAGE128(cur ^ 1, t + 1);

#pragma unroll
      for (int u = 0; u < 2; ++u) {
        int t64 = 2 * t + u;
        if (t64 <= tmax64) {
          const u16* Kb = Ks[cur] + u * 4096;
          const u16* Vb = Vt[cur] + u * 4096;

          f32x4 St[4][2];
#pragma unroll
          for (int j = 0; j < 4; j++)
#pragma unroll
            for (int i = 0; i < 2; i++) St[j][i] = (f32x4)0.0f;
          __builtin_amdgcn_s_setprio(1);
#pragma unroll
          for (int kk = 0; kk < 2; ++kk) {
            bf16x8 kbf[4];
#pragma unroll
            for (int j = 0; j < 4; j++)
              kbf[j] = load_frag16(swz(Kb, j * 16 + lr, kk * 64 + lg * 16));
#pragma unroll
            for (int j = 0; j < 4; j++)
#pragma unroll
              for (int i = 0; i < 2; i++)
                St[j][i] = __builtin_amdgcn_mfma_f32_16x16x32_bf16(kbf[j], qf[i][kk], St[j][i], 0, 0, 0);
          }
          __builtin_amdgcn_s_setprio(0);

          if (t64 == tmax64) {  // diagonal tile: mask k > q
#pragma unroll
            for (int j = 0; j < 4; j++)
#pragma unroll
              for (int i = 0; i < 2; i++)
#pragma unroll
                for (int r = 0; r < 4; r++) {
                  int kabs = t64 * 64 + j * 16 + lg * 4 + r;
                  int qabs = qb + w * 32 + i * 16 + lr;
                  if (kabs > qabs) St[j][i][r] = -1e30f;
                }
          }

          // lane-local online softmax (log2 domain), defer-max THR=10
#pragma unroll
          for (int i = 0; i < 2; ++i) {
            float tj[4];
#pragma unroll
            for (int j = 0; j < 4; j++)
              tj[j] = fmaxf(fmaxf(St[j][i][0], St[j][i][1]),
                            fmaxf(St[j][i][2], St[j][i][3]));
            float tm = fmaxf(fmaxf(tj[0], tj[1]), fmaxf(tj[2], tj[3]));
            tm = fmaxf(tm, __shfl_xor(tm, 16));
            tm = fmaxf(tm, __shfl_xor(tm, 32));
            if (!__all((int)(tm <= m_st[i] + 10.0f))) {
              float mn = fmaxf(m_st[i], tm);
              float fsc = exp2_fast(m_st[i] - mn);
              m_st[i] = mn;
              l_st[i] *= fsc;
#pragma unroll
              for (int r = 0; r < 4; ++r) {
                float ff = __shfl(fsc, lg * 4 + r);
#pragma unroll
                for (int jd = 0; jd < 4; jd++) of[i][jd][r] *= ff;
              }
            }
            float rj[4];
#pragma unroll
            for (int j = 0; j < 4; ++j) {
              float p0 = exp2_fast(St[j][i][0] - m_st[i]);
              float p1 = exp2_fast(St[j][i][1] - m_st[i]);
              float p2 = exp2_fast(St[j][i][2] - m_st[i]);
              float p3 = exp2_fast(St[j][i][3] - m_st[i]);
              rj[j] = (p0 + p1) + (p2 + p3);
              uint2 pk;
              pk.x = cvt_pk_bf16(p0, p1);
              pk.y = cvt_pk_bf16(p2, p3);
              *(uint2*)swzw(PlW, i * 16 + lr, j * 32 + lg * 8) = pk;
            }
            float rs = (rj[0] + rj[1]) + (rj[2] + rj[3]);
            rs += __shfl_xor(rs, 16);
            rs += __shfl_xor(rs, 32);
            l_st[i] += rs;
          }

          // PV: O[q][d] += P[q][k] * V[k][d]
          __builtin_amdgcn_s_setprio(1);
#pragma unroll
          for (int ks = 0; ks < 2; ++ks) {
            bf16x8 ap[2], vbf[4];
#pragma unroll
            for (int i = 0; i < 2; i++)
              ap[i] = load_frag16(swz(PlW, i * 16 + lr, ks * 64 + lg * 16));
#pragma unroll
            for (int jd = 0; jd < 4; jd++)
              vbf[jd] = load_frag16(swz(Vb, jd * 16 + lr, ks * 64 + lg * 16));
#pragma unroll
            for (int i = 0; i < 2; i++)
#pragma unroll
              for (int jd = 0; jd < 4; jd++)
                of[i][jd] = __builtin_amdgcn_mfma_f32_16x16x32_bf16(ap[i], vbf[jd], of[i][jd], 0, 0, 0);
          }
          __builtin_amdgcn_s_setprio(0);
        }
      }
    }
    __syncthreads();  // protect staging buffers before next half / exit

    // epilogue: O /= lsum, store bf16 head-merged
#pragma unroll
    for (int i = 0; i < 2; i++) {
#pragma unroll
      for (int r = 0; r < 4; r++) {
        float ls = __shfl(l_st[i], lg * 4 + r);
        float inv = 1.0f / ls;
#pragma unroll
        for (int jd = 0; jd < 4; jd++) {
          int row = qb + w * 32 + i * 16 + lg * 4 + r;
          int col = h * 64 + jd * 16 + lr;
          attnb[((size_t)b * 2048 + row) * 1024 + col] = f32_to_bf16(of[i][jd][r] * inv);
        }
      }
    }
  }
#undef STAGE128
}

extern "C" void kernel_launch(void* const* d_in, const int* in_sizes, int n_in,
                              void* d_out, int out_size, void* d_ws, size_t ws_size,
                              hipStream_t stream) {
  const float* x = (const float*)d_in[0];
  const float* Wqkv = (const float*)d_in[1];
  const float* bqkv = (const float*)d_in[2];
  const float* Wproj = (const float*)d_in[3];
  const float* bproj = (const float*)d_in[4];
  float* out = (float*)d_out;

  char* ws = (char*)d_ws;
  u16* xb    = (u16*)(ws);                 // 8192*1024*2 = 16,777,216
  u16* wqT   = (u16*)(ws + 16777216);      // 3072*1024*2 =  6,291,456
  u16* wpT   = (u16*)(ws + 23068672);      // 1024*1024*2 =  2,097,152
  u16* qkb   = (u16*)(ws + 25165824);      // 8192*2048*2 = 33,554,432 (Q|K)
  u16* vTg   = (u16*)(ws + 58720256);      // 64*64*2048*2= 16,777,216
  u16* attnb = (u16*)(ws + 75497472);      // 8192*1024*2 = 16,777,216  (total ~92MB)

  prep_kernel<<<dim3(384, 32), 256, 0, stream>>>(Wqkv, wqT, Wproj, wpT, x, xb);
  gemm_bf16<2><<<dim3(24, 64), 256, 0, stream>>>(xb, wqT, bqkv, (void*)qkb, 8192, 3072, 1024, vTg);
  attn_kernel<<<dim3(8, 64), 256, 0, stream>>>(qkb, vTg, attnb);
  gemm_bf16<0><<<dim3(8, 64), 256, 0, stream>>>(attnb, wpT, bproj, (void*)out, 8192, 1024, 1024, nullptr);
}